// Round 14
// baseline (25.175 us; speedup 1.0000x reference)
//
#include <hip/hip_runtime.h>
#include <math.h>

#define KNN 8
#define QPB 32          // queries per block
#define SUB 16          // sub-lanes per query
#define BLK 512         // QPB*SUB threads, 8 waves
#define CAP 512         // staged rows per LDS tile (== BLK: 1 row/thread)

// Single fused kernel, single dispatch, XCD-swizzled.
// R14: packed (d,idx) u64 sort keys (1 cmp = exact lexicographic order),
// difference-form distance, and issue-early double-buffered staging.
__launch_bounds__(BLK, 4)
__global__ void knn_one(const float* __restrict__ x1,
                        const float* __restrict__ x2,
                        const int* __restrict__ b1,
                        const int* __restrict__ b2,
                        int N, int ROW, float scale,
                        unsigned long long* __restrict__ slot,
                        float* __restrict__ out) {
  __shared__ float4 c4[2][CAP];       // {x, y, z, unused}
  __shared__ int   bs[2][CAP];        // batch id per staged row
  __shared__ int   s_info[2];         // block staging range {s1, e1}
  __shared__ float wred[BLK / 64];

  // Bijective XCD swizzle: consecutive work-ids (same batch) share an XCD L2.
  const int nwg = (int)gridDim.x;
  const int xcd = (int)blockIdx.x & 7, pos = (int)blockIdx.x >> 3;
  const int q8 = nwg >> 3, r8 = nwg & 7;
  const int bid = (xcd < r8) ? xcd * (q8 + 1) + pos
                             : r8 * (q8 + 1) + (xcd - r8) * q8 + pos;

  const int tid  = threadIdx.x;
  const int lane = tid & 63;
  const int wv   = tid >> 6;          // 0..7
  const int qi   = tid >> 4;          // 0..31 query within block
  const int sub  = tid & (SUB - 1);   // lane in 16-group; owned dim base
  const int q0   = bid * QPB;
  const int q    = min(q0 + qi, N - 1);
  const int qlast = min(q0 + QPB - 1, N - 1);

  // Hoisted x2 reads: coords + this lane's 8 owned feature dims.
  float qx, qy, qz; int mybatch;
  float f2v[KNN];
  {
    const float* c2 = x2 + (size_t)q * ROW;
    qx = c2[0]; qy = c2[1]; qz = c2[2];
    mybatch = b2[q];
    const float* f2 = c2 + 3 + sub;
#pragma unroll
    for (int t = 0; t < KNN; ++t) f2v[t] = f2[16 * t];
  }

  // Wave-cooperative lower_bound on b1 (64-way fanout, ~3 dependent rounds).
  if (wv < 2) {
    const int bb = (wv == 0) ? b2[q0] : b2[qlast];
    const int target = bb + wv;
    int lo = 0, hi = N;
    while (lo < hi) {
      int step = (hi - lo + 63) >> 6;
      int p = lo + lane * step;
      bool pred = (p < hi) && (b1[p] < target);
      int c = __popcll(__ballot(pred));
      if (c == 0) { hi = lo; break; }
      int nlo = lo + (c - 1) * step + 1;
      hi = min(hi, lo + c * step);
      lo = nlo;
    }
    if (lane == 0) s_info[wv] = lo;
  }

  // Sorted top-8 as packed keys: (float_bits(d) << 32) | idx.
  // d >= 0 -> bits monotone -> u64 order == lexicographic (d, idx).
  unsigned long long K[KNN];
  const unsigned long long KINIT = 0x7F800000ULL << 32;   // (inf, 0)
#pragma unroll
  for (int k = 0; k < KNN; ++k) K[k] = KINIT;

  __syncthreads();
  const int s1v = s_info[0], e1v = s_info[1];

  // Prologue: stage tile 0 (1 row/thread).
  int t0 = s1v, t1 = min(t0 + CAP, e1v), buf = 0;
  {
    int i = t0 + tid;
    if (i < t1) {
      const float* p = x1 + (size_t)i * ROW;
      c4[0][i - t0] = make_float4(p[0], p[1], p[2], 0.f);
      bs[0][i - t0] = b1[i];
    }
  }
  __syncthreads();

  while (true) {
    const int tn0 = t1, tn1 = min(tn0 + CAP, e1v);
    // Issue next tile's loads early (in flight during the scan).
    float nx = 0.f, ny = 0.f, nz = 0.f; int nb = 0;
    const bool have_next = tn0 < e1v;
    const int ni = tn0 + tid;
    if (have_next && ni < tn1) {
      const float* p = x1 + (size_t)ni * ROW;
      nx = p[0]; ny = p[1]; nz = p[2]; nb = b1[ni];
    }
    // Scan current tile; foreign-batch rows masked to key=~0 (never inserted).
    for (int j = t0 + sub; j < t1; j += SUB) {
      float4 c = c4[buf][j - t0];
      int bv = bs[buf][j - t0];
      float dx = qx - c.x, dy = qy - c.y, dz = qz - c.z;
      float d = fmaf(dx, dx, fmaf(dy, dy, dz * dz));
      unsigned long long key =
          ((unsigned long long)__float_as_uint(d) << 32) | (unsigned)j;
      key = (bv == mybatch) ? key : ~0ULL;
      bool lt[KNN];
#pragma unroll
      for (int k = 0; k < KNN; ++k) lt[k] = key < K[k];
#pragma unroll
      for (int k = KNN - 1; k > 0; --k)
        K[k] = lt[k - 1] ? K[k - 1] : (lt[k] ? key : K[k]);
      K[0] = lt[0] ? key : K[0];
    }
    if (!have_next) break;
    // Write next tile into the other buffer (waits its loads), flip.
    if (ni < tn1) {
      c4[buf ^ 1][ni - tn0] = make_float4(nx, ny, nz, 0.f);
      bs[buf ^ 1][ni - tn0] = nb;
    }
    __syncthreads();
    t0 = tn0; t1 = tn1; buf ^= 1;
  }

  // Fused exact merge + gather. Round r: u64-min across the 16-lane group
  // (butterfly => converged in every lane) == lexicographic (d, idx) min;
  // pop the owner; every lane immediately issues that row's 8 dim loads.
  float acc[KNN];
#pragma unroll
  for (int t = 0; t < KNN; ++t) acc[t] = 0.f;
  float sw = 0.f;
  const float* x1f = x1 + 3 + sub;
#pragma unroll
  for (int r = 0; r < KNN; ++r) {
    unsigned long long h = K[0], b = h;
#pragma unroll
    for (int m = 1; m <= 8; m <<= 1) {
      unsigned long long o = __shfl_xor(b, m);
      b = (o < b) ? o : b;
    }
    if (h == b) {                 // pop winner; identical pads multi-pop harmlessly
#pragma unroll
      for (int k = 0; k < KNN - 1; ++k) K[k] = K[k + 1];
      K[KNN - 1] = KINIT;
    }
    float bd = __uint_as_float((unsigned)(b >> 32));
    int   bi = (int)(unsigned)b;
    float w = 1.0f / fmaxf(bd, 1e-16f);   // d=inf (pad) -> w = 0
    sw += w;
    const float* f = x1f + (size_t)bi * ROW;
#pragma unroll
    for (int t = 0; t < KNN; ++t) acc[t] = fmaf(w, f[16 * t], acc[t]);
  }

  // Epilogue: this lane's 8 dims of its query's squared error.
  float pacc = 0.0f;
  if (q0 + qi < N) {
    float rinv = 1.0f / sw;
#pragma unroll
    for (int t = 0; t < KNN; ++t) {
      float e = fmaf(acc[t], rinv, -f2v[t]);
      pacc += e * e;
    }
  }
#pragma unroll
  for (int off = 32; off > 0; off >>= 1) pacc += __shfl_xor(pacc, off);
  if (lane == 0) wred[wv] = pacc;
  __syncthreads();

  // Publish {TAG(bid) | partial} as one 64-bit agent-scope relaxed store.
  if (tid == 0) {
    float s = 0.0f;
#pragma unroll
    for (int w = 0; w < BLK / 64; ++w) s += wred[w];
    unsigned long long v =
        ((unsigned long long)(0x5A000000u | (unsigned)bid) << 32) |
        (unsigned long long)__float_as_uint(s);
    __hip_atomic_store(&slot[bid], v, __ATOMIC_RELAXED,
                       __HIP_MEMORY_SCOPE_AGENT);
  }

  // Work-block 0 / wave 0: spin-read all slots (deterministic values => any
  // interleaving is bit-identical), fixed-order sum, write result.
  if (bid == 0 && wv == 0) {
    float s = 0.0f;
    for (int r = 0; r * 64 + lane < nwg; ++r) {
      int i = r * 64 + lane;
      unsigned tag = 0x5A000000u | (unsigned)i;
      unsigned long long x = __hip_atomic_load(&slot[i], __ATOMIC_RELAXED,
                                               __HIP_MEMORY_SCOPE_AGENT);
      while ((unsigned)(x >> 32) != tag) {
        __builtin_amdgcn_s_sleep(8);
        x = __hip_atomic_load(&slot[i], __ATOMIC_RELAXED,
                              __HIP_MEMORY_SCOPE_AGENT);
      }
      s += __uint_as_float((unsigned)x);   // lane-local, fixed r-order
    }
#pragma unroll
    for (int off = 32; off > 0; off >>= 1) s += __shfl_xor(s, off);
    if (lane == 0) out[0] = s * scale;
  }
}

extern "C" void kernel_launch(void* const* d_in, const int* in_sizes, int n_in,
                              void* d_out, int out_size, void* d_ws, size_t ws_size,
                              hipStream_t stream) {
  const float* x1 = (const float*)d_in[0];
  const float* x2 = (const float*)d_in[1];
  const int* b1 = (const int*)d_in[2];
  const int* b2 = (const int*)d_in[3];
  int N = in_sizes[2];            // 16384
  int ROW = in_sizes[0] / N;      // 131
  float* out = (float*)d_out;

  int blocks = (N + QPB - 1) / QPB;              // 512
  unsigned long long* slot = (unsigned long long*)d_ws;
  if (ws_size < (size_t)blocks * sizeof(unsigned long long)) return;

  float scale = 1.0f / ((float)N * (float)(ROW - 3));
  knn_one<<<blocks, BLK, 0, stream>>>(x1, x2, b1, b2, N, ROW, scale, slot, out);
}

// Round 15
// 24.740 us; speedup vs baseline: 1.0176x; 1.0176x over previous
//
#include <hip/hip_runtime.h>
#include <math.h>

#define KNN 8
#define QPB 16          // queries per block
#define SUB 16          // sub-lanes per query
#define BLK 256         // QPB*SUB threads, 4 waves
#define CAP 768         // staged rows (covers 2 full batches at +20 sigma)

// Single fused kernel, single dispatch, XCD-swizzled, WHOLE-GRID CO-RESIDENT:
// 1024 blocks x (256 threads, 12.3KB LDS, <=128 VGPR) = exactly 4 blocks/CU.
// Pipeline per block: hoisted x2 loads -> wave-coop range search -> stage
// {x,y,z,batch} -> 16-way sliced scan, branchless u64-key sorted top-8 ->
// fused exact merge+gather -> MSE partial -> slot publish; work-block 0
// spin-reads slots (deterministic values), fixed-order sum -> out.
__launch_bounds__(BLK, 4)
__global__ void knn_one(const float* __restrict__ x1,
                        const float* __restrict__ x2,
                        const int* __restrict__ b1,
                        const int* __restrict__ b2,
                        int N, int ROW, float scale,
                        unsigned long long* __restrict__ slot,
                        float* __restrict__ out) {
  __shared__ float4 c4[CAP];          // {x, y, z, batch_id_bits}
  __shared__ int   s_info[2];         // block staging range {s1, e1}
  __shared__ float wred[BLK / 64];

  // Bijective XCD swizzle: consecutive work-ids (same batch) share an XCD L2.
  const int nwg = (int)gridDim.x;
  const int xcd = (int)blockIdx.x & 7, pos = (int)blockIdx.x >> 3;
  const int q8 = nwg >> 3, r8 = nwg & 7;
  const int bid = (xcd < r8) ? xcd * (q8 + 1) + pos
                             : r8 * (q8 + 1) + (xcd - r8) * q8 + pos;

  const int tid  = threadIdx.x;
  const int lane = tid & 63;
  const int wv   = tid >> 6;          // 0..3
  const int qi   = tid >> 4;          // 0..15 query within block
  const int sub  = tid & (SUB - 1);   // lane in 16-group; owned dim base
  const int q0   = bid * QPB;
  const int q    = min(q0 + qi, N - 1);
  const int qlast = min(q0 + QPB - 1, N - 1);

  // Hoisted x2 reads: coords + this lane's 8 owned feature dims
  // (f2v consumed only in the epilogue -> pure prefetch overlap).
  float qx, qy, qz; int mybatch;
  float f2v[KNN];
  {
    const float* c2 = x2 + (size_t)q * ROW;
    qx = c2[0]; qy = c2[1]; qz = c2[2];
    mybatch = b2[q];
    const float* f2 = c2 + 3 + sub;
#pragma unroll
    for (int t = 0; t < KNN; ++t) f2v[t] = f2[16 * t];
  }

  // Wave-cooperative lower_bound on b1 (64-way fanout, ~3 dependent rounds).
  if (wv < 2) {
    const int bb = (wv == 0) ? b2[q0] : b2[qlast];
    const int target = bb + wv;       // wv0: lb(b_first), wv1: lb(b_last+1)
    int lo = 0, hi = N;
    while (lo < hi) {
      int step = (hi - lo + 63) >> 6;
      int p = lo + lane * step;
      bool pred = (p < hi) && (b1[p] < target);
      int c = __popcll(__ballot(pred));
      if (c == 0) { hi = lo; break; }
      int nlo = lo + (c - 1) * step + 1;
      hi = min(hi, lo + c * step);
      lo = nlo;
    }
    if (lane == 0) s_info[wv] = lo;
  }

  // Sorted top-8 as packed keys: (float_bits(d) << 32) | idx.
  // d >= 0 -> bits monotone -> u64 order == lexicographic (d, idx) exactly.
  unsigned long long K[KNN];
  const unsigned long long KINIT = 0x7F800000ULL << 32;   // (inf, 0)
#pragma unroll
  for (int k = 0; k < KNN; ++k) K[k] = KINIT;

  __syncthreads();
  const int s1v = s_info[0], e1v = s_info[1];

  for (int t0 = s1v; t0 < e1v; t0 += CAP) {   // one tile in practice
    const int t1 = min(t0 + CAP, e1v);
    __syncthreads();
    for (int i = t0 + tid; i < t1; i += BLK) {
      const float* p = x1 + (size_t)i * ROW;
      c4[i - t0] = make_float4(p[0], p[1], p[2], __int_as_float(b1[i]));
    }
    __syncthreads();
    // All lanes scan the tile; foreign-batch rows masked to key=~0.
    for (int j = t0 + sub; j < t1; j += SUB) {
      float4 c = c4[j - t0];
      float dx = qx - c.x, dy = qy - c.y, dz = qz - c.z;
      float d = fmaf(dx, dx, fmaf(dy, dy, dz * dz));
      unsigned long long key =
          ((unsigned long long)__float_as_uint(d) << 32) | (unsigned)j;
      key = (__float_as_int(c.w) == mybatch) ? key : ~0ULL;
      // Branchless sorted insert (strict u64 < == lexicographic (d, idx)).
      bool lt[KNN];
#pragma unroll
      for (int k = 0; k < KNN; ++k) lt[k] = key < K[k];
#pragma unroll
      for (int k = KNN - 1; k > 0; --k)
        K[k] = lt[k - 1] ? K[k - 1] : (lt[k] ? key : K[k]);
      K[0] = lt[0] ? key : K[0];
    }
  }

  // Fused exact merge + gather. Round r: u64-min across the 16-lane group
  // (butterfly => converged in every lane) == lexicographic (d, idx) min;
  // pop the owner; every lane immediately issues that row's 8 dim loads
  // (rounds' loads pipeline; next round's shfls don't depend on them).
  float acc[KNN];
#pragma unroll
  for (int t = 0; t < KNN; ++t) acc[t] = 0.f;
  float sw = 0.f;
  const float* x1f = x1 + 3 + sub;
#pragma unroll
  for (int r = 0; r < KNN; ++r) {
    unsigned long long h = K[0], b = h;
#pragma unroll
    for (int m = 1; m <= 8; m <<= 1) {
      unsigned long long o = __shfl_xor(b, m);
      b = (o < b) ? o : b;
    }
    if (h == b) {                 // pop winner; identical pads multi-pop harmlessly
#pragma unroll
      for (int k = 0; k < KNN - 1; ++k) K[k] = K[k + 1];
      K[KNN - 1] = KINIT;
    }
    float bd = __uint_as_float((unsigned)(b >> 32));
    int   bi = (int)(unsigned)b;
    float w = 1.0f / fmaxf(bd, 1e-16f);   // d=inf (pad) -> w = 0
    sw += w;
    const float* f = x1f + (size_t)bi * ROW;
#pragma unroll
    for (int t = 0; t < KNN; ++t) acc[t] = fmaf(w, f[16 * t], acc[t]);
  }

  // Epilogue: this lane's 8 dims of its query's squared error.
  float pacc = 0.0f;
  if (q0 + qi < N) {
    float rinv = 1.0f / sw;
#pragma unroll
    for (int t = 0; t < KNN; ++t) {
      float e = fmaf(acc[t], rinv, -f2v[t]);
      pacc += e * e;
    }
  }
#pragma unroll
  for (int off = 32; off > 0; off >>= 1) pacc += __shfl_xor(pacc, off);
  if (lane == 0) wred[wv] = pacc;
  __syncthreads();

  // Publish {TAG(bid) | partial} as one 64-bit agent-scope relaxed store.
  if (tid == 0) {
    float s = (wred[0] + wred[1]) + (wred[2] + wred[3]);
    unsigned long long v =
        ((unsigned long long)(0x5A000000u | (unsigned)bid) << 32) |
        (unsigned long long)__float_as_uint(s);
    __hip_atomic_store(&slot[bid], v, __ATOMIC_RELAXED,
                       __HIP_MEMORY_SCOPE_AGENT);
  }

  // Work-block 0 / wave 0: spin-read all slots (deterministic values => any
  // interleaving is bit-identical), fixed-order sum, write result.
  if (bid == 0 && wv == 0) {
    float s = 0.0f;
    for (int r = 0; r * 64 + lane < nwg; ++r) {
      int i = r * 64 + lane;
      unsigned tag = 0x5A000000u | (unsigned)i;
      unsigned long long x = __hip_atomic_load(&slot[i], __ATOMIC_RELAXED,
                                               __HIP_MEMORY_SCOPE_AGENT);
      while ((unsigned)(x >> 32) != tag) {
        __builtin_amdgcn_s_sleep(8);
        x = __hip_atomic_load(&slot[i], __ATOMIC_RELAXED,
                              __HIP_MEMORY_SCOPE_AGENT);
      }
      s += __uint_as_float((unsigned)x);   // lane-local, fixed r-order
    }
#pragma unroll
    for (int off = 32; off > 0; off >>= 1) s += __shfl_xor(s, off);
    if (lane == 0) out[0] = s * scale;
  }
}

extern "C" void kernel_launch(void* const* d_in, const int* in_sizes, int n_in,
                              void* d_out, int out_size, void* d_ws, size_t ws_size,
                              hipStream_t stream) {
  const float* x1 = (const float*)d_in[0];
  const float* x2 = (const float*)d_in[1];
  const int* b1 = (const int*)d_in[2];
  const int* b2 = (const int*)d_in[3];
  int N = in_sizes[2];            // 16384
  int ROW = in_sizes[0] / N;      // 131
  float* out = (float*)d_out;

  int blocks = (N + QPB - 1) / QPB;              // 1024
  unsigned long long* slot = (unsigned long long*)d_ws;
  if (ws_size < (size_t)blocks * sizeof(unsigned long long)) return;

  float scale = 1.0f / ((float)N * (float)(ROW - 3));
  knn_one<<<blocks, BLK, 0, stream>>>(x1, x2, b1, b2, N, ROW, scale, slot, out);
}